// Round 7
// baseline (480.930 us; speedup 1.0000x reference)
//
#include <hip/hip_runtime.h>
#include <hip/hip_bf16.h>

#define IN_DIM   128
#define HIDDEN   128
#define KDIM     256          // 2*IN_DIM
#define TILE_E   32           // edges per wave-tile
#define NTHREADS 512
#define LDBW     264          // sB row pitch in bf16 (528 B; min-phase b128 reads, 0 conflicts measured)

typedef __attribute__((ext_vector_type(8)))  short bf16x8;
typedef __attribute__((ext_vector_type(16))) float f32x16;

__device__ __forceinline__ unsigned short f2bf(float f) {
    union { __hip_bfloat16 h; unsigned short u; } cv;
    cv.h = __float2bfloat16(f);
    return cv.u;
}

// Fused prep: bf16 copies of both embedding tables + W1 transpose->bf16.
__global__ void prep_kernel(const float* __restrict__ pat,
                            const float* __restrict__ cond,
                            const float* __restrict__ W1,
                            unsigned short* __restrict__ pat_bf,
                            unsigned short* __restrict__ cond_bf,
                            unsigned short* __restrict__ W1T,
                            int n_vec, int do_tables) {
    const int w1_units = HIDDEN * KDIM / 8;         // 4096
    const long long total = do_tables ? (2LL * n_vec + w1_units) : w1_units;
    const long long stride = (long long)gridDim.x * blockDim.x;
    for (long long u = blockIdx.x * (long long)blockDim.x + threadIdx.x;
         u < total; u += stride) {
        if (do_tables && u < 2LL * n_vec) {
            int which = (u >= n_vec);
            long long v = which ? u - n_vec : u;
            const float* src = which ? cond : pat;
            unsigned short* dst = which ? cond_bf : pat_bf;
            long long base = v * 8;
            float4 x = *(const float4*)(src + base);
            float4 y = *(const float4*)(src + base + 4);
            unsigned short hv[8];
            hv[0]=f2bf(x.x); hv[1]=f2bf(x.y); hv[2]=f2bf(x.z); hv[3]=f2bf(x.w);
            hv[4]=f2bf(y.x); hv[5]=f2bf(y.y); hv[6]=f2bf(y.z); hv[7]=f2bf(y.w);
            *(uint4*)(dst + base) = *(uint4*)hv;
        } else {
            int idx = (int)(u - (do_tables ? 2LL * n_vec : 0));  // 0..4095
            int c  = idx >> 5;        // hidden col 0..127
            int k0 = (idx & 31) * 8;  // k offset
            unsigned short hv[8];
            #pragma unroll
            for (int j = 0; j < 8; ++j)
                hv[j] = f2bf(W1[(k0 + j) * HIDDEN + c]);
            *(uint4*)(W1T + c * KDIM + k0) = *(uint4*)hv;
        }
    }
}

// Fast path: bf16 tables; single-buffer issue-early pipeline; fold epilogue.
__global__ __launch_bounds__(NTHREADS, 2)   // 2 waves/EU min -> 256-reg budget, no spills
void link_mlp_kernel(const unsigned short* __restrict__ tbl_p,
                     const unsigned short* __restrict__ tbl_c,
                     const int* __restrict__ eidx,
                     const unsigned short* __restrict__ W1T,
                     const float* __restrict__ b1,
                     const float* __restrict__ W2,
                     const float* __restrict__ b2,
                     float* __restrict__ out,
                     int E, int n_nodes, int ntiles)
{
    __shared__ unsigned short sB[HIDDEN * LDBW];   // W1T, padded pitch

    const int t = threadIdx.x;
    #pragma unroll
    for (int it = 0; it < 8; ++it) {
        int ci = it * NTHREADS + t;          // 0..4095
        int c = ci >> 5, j = ci & 31;
        *(uint4*)&sB[c * LDBW + j * 8] = *(const uint4*)(W1T + c * KDIM + j * 8);
    }
    __syncthreads();

    const int w    = t >> 6;
    const int lane = t & 63;
    const int c32  = lane & 31;
    const int hi   = lane >> 5;

    float b1v[4], w2v[4];
    #pragma unroll
    for (int nt = 0; nt < 4; ++nt) {
        int col = nt * 32 + c32;
        b1v[nt] = b1[col];
        w2v[nt] = W2[col];
    }
    const float b2v = b2[0];

    const int wsl = gridDim.x * (NTHREADS / 64);
    int tile = blockIdx.x * (NTHREADS / 64) + w;
    if (tile >= ntiles) return;

    bf16x8 A[16];   // full A-tile for current tile; statically indexed everywhere

    // ---- prologue: indices + all 16 row-loads for first tile ----
    {
        int eC = min(tile * TILE_E + c32, E - 1);
        int np = eidx[eC];     np = min(max(np, 0), n_nodes - 1);
        int nc = eidx[E + eC]; nc = min(max(nc, 0), n_nodes - 1);
        const unsigned short* bp = tbl_p + np * IN_DIM + hi * 8;
        const unsigned short* bc = tbl_c + nc * IN_DIM + hi * 8;
        #pragma unroll
        for (int j = 0; j < 8; ++j) {
            A[j]     = *(const bf16x8*)(bp + j * 16);
            A[8 + j] = *(const bf16x8*)(bc + j * 16);
        }
    }
    int npN = 0, ncN = 0;
    {
        int tn = tile + wsl;
        if (tn < ntiles) {
            int e2 = min(tn * TILE_E + c32, E - 1);
            npN = eidx[e2]; ncN = eidx[E + e2];
        }
    }

    while (true) {
        // ---- MFMA phase: consume A[0..15] in issue order (incremental vmcnt) ----
        f32x16 acc[4];
        #pragma unroll
        for (int nt = 0; nt < 4; ++nt)
            acc[nt] = (f32x16){0.f,0.f,0.f,0.f,0.f,0.f,0.f,0.f,
                               0.f,0.f,0.f,0.f,0.f,0.f,0.f,0.f};
        #pragma unroll
        for (int ks = 0; ks < 16; ++ks) {
            #pragma unroll
            for (int nt = 0; nt < 4; ++nt) {
                bf16x8 bfrag = *(const bf16x8*)
                    &sB[(nt * 32 + c32) * LDBW + ks * 16 + hi * 8];
                acc[nt] = __builtin_amdgcn_mfma_f32_32x32x16_bf16(
                    A[ks], bfrag, acc[nt], 0, 0, 0);
            }
        }

        // ---- issue next tile's loads NOW (A regs just died); epilogue hides latency ----
        const int tn = tile + wsl;
        if (tn < ntiles) {
            int np = min(max(npN, 0), n_nodes - 1);
            int nc = min(max(ncN, 0), n_nodes - 1);
            const unsigned short* bp = tbl_p + np * IN_DIM + hi * 8;
            const unsigned short* bc = tbl_c + nc * IN_DIM + hi * 8;
            // idx prefetch two tiles out, issued first (oldest in vm queue)
            int tnn = min(tn + wsl, ntiles - 1);
            int e3 = min(tnn * TILE_E + c32, E - 1);
            npN = eidx[e3]; ncN = eidx[E + e3];
            #pragma unroll
            for (int j = 0; j < 8; ++j) {
                A[j]     = *(const bf16x8*)(bp + j * 16);
                A[8 + j] = *(const bf16x8*)(bc + j * 16);
            }
        }

        // ---- epilogue: relu + W2 dot, fold-reduce 16 vals over 32 lanes ----
        float v[16];
        #pragma unroll
        for (int r = 0; r < 16; ++r) {
            float s = 0.f;
            #pragma unroll
            for (int nt = 0; nt < 4; ++nt)
                s += fmaxf(acc[nt][r] + b1v[nt], 0.f) * w2v[nt];
            v[r] = s;
        }
        #pragma unroll
        for (int j = 0; j < 16; ++j) v[j] += __shfl_xor(v[j], 1, 64);
        const bool bb0 = (lane & 1);
        float w8[8];
        #pragma unroll
        for (int j = 0; j < 8; ++j) w8[j] = bb0 ? v[j + 8] : v[j];
        #pragma unroll
        for (int j = 0; j < 8; ++j) w8[j] += __shfl_xor(w8[j], 2, 64);
        const bool bb1 = (lane >> 1) & 1;
        float x4[4];
        #pragma unroll
        for (int j = 0; j < 4; ++j) x4[j] = bb1 ? w8[j + 4] : w8[j];
        #pragma unroll
        for (int j = 0; j < 4; ++j) x4[j] += __shfl_xor(x4[j], 4, 64);
        const bool bb2 = (lane >> 2) & 1;
        float y2[2];
        #pragma unroll
        for (int j = 0; j < 2; ++j) y2[j] = bb2 ? x4[j + 2] : x4[j];
        #pragma unroll
        for (int j = 0; j < 2; ++j) y2[j] += __shfl_xor(y2[j], 8, 64);
        const bool bb3 = (lane >> 3) & 1;
        float z = bb3 ? y2[1] : y2[0];
        z += __shfl_xor(z, 16, 64);

        {
            int r = ((lane & 1) << 3) | (((lane >> 1) & 1) << 2) |
                    (((lane >> 2) & 1) << 1) | ((lane >> 3) & 1);
            int row = (r & 3) + ((r >> 2) << 3) + 4 * hi;
            int erow = tile * TILE_E + row;
            if (!(lane & 16) && erow < E)
                out[erow] = 1.f / (1.f + __expf(-(z + b2v)));
        }

        if (tn >= ntiles) break;
        tile = tn;
    }
}

// Fallback (ws too small for bf16 tables): round-4 structure, f32 gather.
__global__ __launch_bounds__(NTHREADS, 2)
void link_mlp_f32_kernel(const float* __restrict__ pat,
                         const float* __restrict__ cond,
                         const int* __restrict__ eidx,
                         const unsigned short* __restrict__ W1T,
                         const float* __restrict__ b1,
                         const float* __restrict__ W2,
                         const float* __restrict__ b2,
                         float* __restrict__ out,
                         int E, int n_nodes, int ntiles)
{
    __shared__ unsigned short sB[HIDDEN * LDBW];
    __shared__ float sLog[8][TILE_E];

    const int t = threadIdx.x;
    #pragma unroll
    for (int it = 0; it < 8; ++it) {
        int ci = it * NTHREADS + t;
        int c = ci >> 5, j = ci & 31;
        *(uint4*)&sB[c * LDBW + j * 8] = *(const uint4*)(W1T + c * KDIM + j * 8);
    }
    __syncthreads();

    const int w    = t >> 6;
    const int lane = t & 63;
    const int c32  = lane & 31;
    const int hi   = lane >> 5;

    float b1v[4], w2v[4];
    #pragma unroll
    for (int nt = 0; nt < 4; ++nt) {
        int col = nt * 32 + c32;
        b1v[nt] = b1[col];
        w2v[nt] = W2[col];
    }
    const float b2v = b2[0];
    const int wslots = gridDim.x * (NTHREADS / 64);

    for (int tile = blockIdx.x * (NTHREADS / 64) + w; tile < ntiles; tile += wslots) {
        const int e  = tile * TILE_E + c32;
        const int eC = min(e, E - 1);
        int np = eidx[eC];     np = min(max(np, 0), n_nodes - 1);
        int nc = eidx[E + eC]; nc = min(max(nc, 0), n_nodes - 1);

        f32x16 acc[4];
        #pragma unroll
        for (int nt = 0; nt < 4; ++nt)
            acc[nt] = (f32x16){0.f,0.f,0.f,0.f,0.f,0.f,0.f,0.f,
                               0.f,0.f,0.f,0.f,0.f,0.f,0.f,0.f};

        const float* fp = pat  + (long long)np * IN_DIM + hi * 8;
        const float* fc = cond + (long long)nc * IN_DIM + hi * 8;
        #pragma unroll
        for (int ksb = 0; ksb < 4; ++ksb) {
            bf16x8 a[4];
            #pragma unroll
            for (int j = 0; j < 4; ++j) {
                int ks = ksb * 4 + j;
                const float* src = (ks < 8) ? (fp + ks * 16) : (fc + (ks - 8) * 16);
                float4 x = *(const float4*)src;
                float4 y = *(const float4*)(src + 4);
                unsigned short hv[8];
                hv[0]=f2bf(x.x); hv[1]=f2bf(x.y); hv[2]=f2bf(x.z); hv[3]=f2bf(x.w);
                hv[4]=f2bf(y.x); hv[5]=f2bf(y.y); hv[6]=f2bf(y.z); hv[7]=f2bf(y.w);
                a[j] = *(bf16x8*)hv;
            }
            #pragma unroll
            for (int j = 0; j < 4; ++j) {
                int ks = ksb * 4 + j;
                #pragma unroll
                for (int nt = 0; nt < 4; ++nt) {
                    bf16x8 b = *(const bf16x8*)
                        &sB[(nt * 32 + c32) * LDBW + ks * 16 + hi * 8];
                    acc[nt] = __builtin_amdgcn_mfma_f32_32x32x16_bf16(
                        a[j], b, acc[nt], 0, 0, 0);
                }
            }
        }

        float p[16];
        #pragma unroll
        for (int r = 0; r < 16; ++r) {
            float s = 0.f;
            #pragma unroll
            for (int nt = 0; nt < 4; ++nt)
                s += fmaxf(acc[nt][r] + b1v[nt], 0.f) * w2v[nt];
            p[r] = s;
        }
        #pragma unroll
        for (int off = 1; off < 32; off <<= 1)
            #pragma unroll
            for (int r = 0; r < 16; ++r)
                p[r] += __shfl_xor(p[r], off, 64);
        if (c32 == 0) {
            #pragma unroll
            for (int r = 0; r < 16; ++r)
                sLog[w][(r & 3) + 8 * (r >> 2) + 4 * hi] = p[r];
        }
        float x  = sLog[w][c32] + b2v;
        float sg = 1.f / (1.f + __expf(-x));
        if (hi == 0 && e < E) out[e] = sg;
    }
}

extern "C" void kernel_launch(void* const* d_in, const int* in_sizes, int n_in,
                              void* d_out, int out_size, void* d_ws, size_t ws_size,
                              hipStream_t stream) {
    const float* pat  = (const float*)d_in[0];
    const float* cond = (const float*)d_in[1];
    const int*   eidx = (const int*)d_in[2];     // int64 in reference -> int32 on device
    const float* W1   = (const float*)d_in[3];
    const float* b1   = (const float*)d_in[4];
    const float* W2   = (const float*)d_in[5];
    const float* b2   = (const float*)d_in[6];
    float*       out  = (float*)d_out;

    const int E       = in_sizes[2] / 2;
    const int n_nodes = in_sizes[0] / IN_DIM;
    const int ntiles  = (E + TILE_E - 1) / TILE_E;

    // ws layout: [0,64K) W1T bf16 | pat_bf | cond_bf
    unsigned short* W1T = (unsigned short*)d_ws;
    const size_t tbl_bytes = (size_t)n_nodes * IN_DIM * 2;
    unsigned short* pat_bf  = (unsigned short*)((char*)d_ws + 65536);
    unsigned short* cond_bf = (unsigned short*)((char*)d_ws + 65536 + tbl_bytes);
    const bool use_tbl = ws_size >= 65536 + 2 * tbl_bytes;

    const int n_vec = n_nodes * IN_DIM / 8;
    prep_kernel<<<2048, 256, 0, stream>>>(pat, cond, W1, pat_bf, cond_bf, W1T,
                                          n_vec, use_tbl ? 1 : 0);

    const int nblocks = 512;
    if (use_tbl) {
        link_mlp_kernel<<<nblocks, NTHREADS, 0, stream>>>(
            pat_bf, cond_bf, eidx, W1T, b1, W2, b2, out, E, n_nodes, ntiles);
    } else {
        link_mlp_f32_kernel<<<nblocks, NTHREADS, 0, stream>>>(
            pat, cond, eidx, W1T, b1, W2, b2, out, E, n_nodes, ntiles);
    }
}

// Round 8
// 439.001 us; speedup vs baseline: 1.0955x; 1.0955x over previous
//
#include <hip/hip_runtime.h>
#include <hip/hip_bf16.h>

#define IN_DIM   128
#define HIDDEN   128
#define KDIM     256          // 2*IN_DIM
#define TILE_E   32           // edges per wave-tile
#define NTHREADS 512
#define LDBW     264          // sB row pitch in bf16 (528 B; conflict-free b128 pattern, 0 measured)

typedef __attribute__((ext_vector_type(8)))  short bf16x8;
typedef __attribute__((ext_vector_type(16))) float f32x16;

__device__ __forceinline__ unsigned short f2bf(float f) {
    union { __hip_bfloat16 h; unsigned short u; } cv;
    cv.h = __float2bfloat16(f);
    return cv.u;
}

// Fused prep: bf16 copies of both embedding tables + W1 transpose->bf16.
__global__ void prep_kernel(const float* __restrict__ pat,
                            const float* __restrict__ cond,
                            const float* __restrict__ W1,
                            unsigned short* __restrict__ pat_bf,
                            unsigned short* __restrict__ cond_bf,
                            unsigned short* __restrict__ W1T,
                            int n_vec, int do_tables) {
    const int w1_units = HIDDEN * KDIM / 8;         // 4096
    const long long total = do_tables ? (2LL * n_vec + w1_units) : w1_units;
    const long long stride = (long long)gridDim.x * blockDim.x;
    for (long long u = blockIdx.x * (long long)blockDim.x + threadIdx.x;
         u < total; u += stride) {
        if (do_tables && u < 2LL * n_vec) {
            int which = (u >= n_vec);
            long long v = which ? u - n_vec : u;
            const float* src = which ? cond : pat;
            unsigned short* dst = which ? cond_bf : pat_bf;
            long long base = v * 8;
            float4 x = *(const float4*)(src + base);
            float4 y = *(const float4*)(src + base + 4);
            unsigned short hv[8];
            hv[0]=f2bf(x.x); hv[1]=f2bf(x.y); hv[2]=f2bf(x.z); hv[3]=f2bf(x.w);
            hv[4]=f2bf(y.x); hv[5]=f2bf(y.y); hv[6]=f2bf(y.z); hv[7]=f2bf(y.w);
            *(uint4*)(dst + base) = *(uint4*)hv;
        } else {
            int idx = (int)(u - (do_tables ? 2LL * n_vec : 0));  // 0..4095
            int c  = idx >> 5;        // hidden col 0..127
            int k0 = (idx & 31) * 8;  // k offset
            unsigned short hv[8];
            #pragma unroll
            for (int j = 0; j < 8; ++j)
                hv[j] = f2bf(W1[(k0 + j) * HIDDEN + c]);
            *(uint4*)(W1T + c * KDIM + k0) = *(uint4*)hv;
        }
    }
}

// Fast path: bf16 tables; single-buffer issue-early pipeline; fold epilogue.
// amdgpu_waves_per_eu(2,2): PIN allocator to 2 waves/EU -> 256-reg budget.
// Without the max, the backend targets the LDS-derived 4 waves/EU and spills
// (rounds 6/7: VGPR_Count=128 + 364 MB scratch writes).
__global__ __launch_bounds__(NTHREADS)
__attribute__((amdgpu_waves_per_eu(2, 2)))
void link_mlp_kernel(const unsigned short* __restrict__ tbl_p,
                     const unsigned short* __restrict__ tbl_c,
                     const int* __restrict__ eidx,
                     const unsigned short* __restrict__ W1T,
                     const float* __restrict__ b1,
                     const float* __restrict__ W2,
                     const float* __restrict__ b2,
                     float* __restrict__ out,
                     int E, int n_nodes, int ntiles)
{
    __shared__ unsigned short sB[HIDDEN * LDBW];   // W1T, padded pitch

    const int t = threadIdx.x;
    #pragma unroll
    for (int it = 0; it < 8; ++it) {
        int ci = it * NTHREADS + t;          // 0..4095
        int c = ci >> 5, j = ci & 31;
        *(uint4*)&sB[c * LDBW + j * 8] = *(const uint4*)(W1T + c * KDIM + j * 8);
    }
    __syncthreads();

    const int w    = t >> 6;
    const int lane = t & 63;
    const int c32  = lane & 31;
    const int hi   = lane >> 5;

    float b1v[4], w2v[4];
    #pragma unroll
    for (int nt = 0; nt < 4; ++nt) {
        int col = nt * 32 + c32;
        b1v[nt] = b1[col];
        w2v[nt] = W2[col];
    }
    const float b2v = b2[0];

    const int wsl = gridDim.x * (NTHREADS / 64);
    int tile = blockIdx.x * (NTHREADS / 64) + w;
    if (tile >= ntiles) return;

    bf16x8 A[16];   // full A-tile for current tile; statically indexed everywhere

    // ---- prologue: indices + all 16 row-loads for first tile ----
    {
        int eC = min(tile * TILE_E + c32, E - 1);
        int np = eidx[eC];     np = min(max(np, 0), n_nodes - 1);
        int nc = eidx[E + eC]; nc = min(max(nc, 0), n_nodes - 1);
        const unsigned short* bp = tbl_p + np * IN_DIM + hi * 8;
        const unsigned short* bc = tbl_c + nc * IN_DIM + hi * 8;
        #pragma unroll
        for (int j = 0; j < 8; ++j) {
            A[j]     = *(const bf16x8*)(bp + j * 16);
            A[8 + j] = *(const bf16x8*)(bc + j * 16);
        }
    }
    int npN = 0, ncN = 0;
    {
        int tn = tile + wsl;
        if (tn < ntiles) {
            int e2 = min(tn * TILE_E + c32, E - 1);
            npN = eidx[e2]; ncN = eidx[E + e2];
        }
    }

    while (true) {
        // ---- MFMA phase: consume A[0..15] in issue order (incremental vmcnt) ----
        f32x16 acc[4];
        #pragma unroll
        for (int nt = 0; nt < 4; ++nt)
            acc[nt] = (f32x16){0.f,0.f,0.f,0.f,0.f,0.f,0.f,0.f,
                               0.f,0.f,0.f,0.f,0.f,0.f,0.f,0.f};
        #pragma unroll
        for (int ks = 0; ks < 16; ++ks) {
            #pragma unroll
            for (int nt = 0; nt < 4; ++nt) {
                bf16x8 bfrag = *(const bf16x8*)
                    &sB[(nt * 32 + c32) * LDBW + ks * 16 + hi * 8];
                acc[nt] = __builtin_amdgcn_mfma_f32_32x32x16_bf16(
                    A[ks], bfrag, acc[nt], 0, 0, 0);
            }
        }

        // ---- issue next tile's loads NOW (A regs just died); epilogue hides latency ----
        const int tn = tile + wsl;
        if (tn < ntiles) {
            int np = min(max(npN, 0), n_nodes - 1);
            int nc = min(max(ncN, 0), n_nodes - 1);
            const unsigned short* bp = tbl_p + np * IN_DIM + hi * 8;
            const unsigned short* bc = tbl_c + nc * IN_DIM + hi * 8;
            // idx prefetch two tiles out, issued first (oldest in vm queue)
            int tnn = min(tn + wsl, ntiles - 1);
            int e3 = min(tnn * TILE_E + c32, E - 1);
            npN = eidx[e3]; ncN = eidx[E + e3];
            #pragma unroll
            for (int j = 0; j < 8; ++j) {
                A[j]     = *(const bf16x8*)(bp + j * 16);
                A[8 + j] = *(const bf16x8*)(bc + j * 16);
            }
        }

        // ---- epilogue: relu + W2 dot, fold-reduce 16 vals over 32 lanes ----
        float v[16];
        #pragma unroll
        for (int r = 0; r < 16; ++r) {
            float s = 0.f;
            #pragma unroll
            for (int nt = 0; nt < 4; ++nt)
                s += fmaxf(acc[nt][r] + b1v[nt], 0.f) * w2v[nt];
            v[r] = s;
        }
        #pragma unroll
        for (int j = 0; j < 16; ++j) v[j] += __shfl_xor(v[j], 1, 64);
        const bool bb0 = (lane & 1);
        float w8[8];
        #pragma unroll
        for (int j = 0; j < 8; ++j) w8[j] = bb0 ? v[j + 8] : v[j];
        #pragma unroll
        for (int j = 0; j < 8; ++j) w8[j] += __shfl_xor(w8[j], 2, 64);
        const bool bb1 = (lane >> 1) & 1;
        float x4[4];
        #pragma unroll
        for (int j = 0; j < 4; ++j) x4[j] = bb1 ? w8[j + 4] : w8[j];
        #pragma unroll
        for (int j = 0; j < 4; ++j) x4[j] += __shfl_xor(x4[j], 4, 64);
        const bool bb2 = (lane >> 2) & 1;
        float y2[2];
        #pragma unroll
        for (int j = 0; j < 2; ++j) y2[j] = bb2 ? x4[j + 2] : x4[j];
        #pragma unroll
        for (int j = 0; j < 2; ++j) y2[j] += __shfl_xor(y2[j], 8, 64);
        const bool bb3 = (lane >> 3) & 1;
        float z = bb3 ? y2[1] : y2[0];
        z += __shfl_xor(z, 16, 64);

        {
            int r = ((lane & 1) << 3) | (((lane >> 1) & 1) << 2) |
                    (((lane >> 2) & 1) << 1) | ((lane >> 3) & 1);
            int row = (r & 3) + ((r >> 2) << 3) + 4 * hi;
            int erow = tile * TILE_E + row;
            if (!(lane & 16) && erow < E)
                out[erow] = 1.f / (1.f + __expf(-(z + b2v)));
        }

        if (tn >= ntiles) break;
        tile = tn;
    }
}

// Fallback (ws too small for bf16 tables): round-4 structure, f32 gather.
__global__ __launch_bounds__(NTHREADS)
__attribute__((amdgpu_waves_per_eu(2, 2)))
void link_mlp_f32_kernel(const float* __restrict__ pat,
                         const float* __restrict__ cond,
                         const int* __restrict__ eidx,
                         const unsigned short* __restrict__ W1T,
                         const float* __restrict__ b1,
                         const float* __restrict__ W2,
                         const float* __restrict__ b2,
                         float* __restrict__ out,
                         int E, int n_nodes, int ntiles)
{
    __shared__ unsigned short sB[HIDDEN * LDBW];
    __shared__ float sLog[8][TILE_E];

    const int t = threadIdx.x;
    #pragma unroll
    for (int it = 0; it < 8; ++it) {
        int ci = it * NTHREADS + t;
        int c = ci >> 5, j = ci & 31;
        *(uint4*)&sB[c * LDBW + j * 8] = *(const uint4*)(W1T + c * KDIM + j * 8);
    }
    __syncthreads();

    const int w    = t >> 6;
    const int lane = t & 63;
    const int c32  = lane & 31;
    const int hi   = lane >> 5;

    float b1v[4], w2v[4];
    #pragma unroll
    for (int nt = 0; nt < 4; ++nt) {
        int col = nt * 32 + c32;
        b1v[nt] = b1[col];
        w2v[nt] = W2[col];
    }
    const float b2v = b2[0];
    const int wslots = gridDim.x * (NTHREADS / 64);

    for (int tile = blockIdx.x * (NTHREADS / 64) + w; tile < ntiles; tile += wslots) {
        const int e  = tile * TILE_E + c32;
        const int eC = min(e, E - 1);
        int np = eidx[eC];     np = min(max(np, 0), n_nodes - 1);
        int nc = eidx[E + eC]; nc = min(max(nc, 0), n_nodes - 1);

        f32x16 acc[4];
        #pragma unroll
        for (int nt = 0; nt < 4; ++nt)
            acc[nt] = (f32x16){0.f,0.f,0.f,0.f,0.f,0.f,0.f,0.f,
                               0.f,0.f,0.f,0.f,0.f,0.f,0.f,0.f};

        const float* fp = pat  + (long long)np * IN_DIM + hi * 8;
        const float* fc = cond + (long long)nc * IN_DIM + hi * 8;
        #pragma unroll
        for (int ksb = 0; ksb < 4; ++ksb) {
            bf16x8 a[4];
            #pragma unroll
            for (int j = 0; j < 4; ++j) {
                int ks = ksb * 4 + j;
                const float* src = (ks < 8) ? (fp + ks * 16) : (fc + (ks - 8) * 16);
                float4 x = *(const float4*)src;
                float4 y = *(const float4*)(src + 4);
                unsigned short hv[8];
                hv[0]=f2bf(x.x); hv[1]=f2bf(x.y); hv[2]=f2bf(x.z); hv[3]=f2bf(x.w);
                hv[4]=f2bf(y.x); hv[5]=f2bf(y.y); hv[6]=f2bf(y.z); hv[7]=f2bf(y.w);
                a[j] = *(bf16x8*)hv;
            }
            #pragma unroll
            for (int j = 0; j < 4; ++j) {
                int ks = ksb * 4 + j;
                #pragma unroll
                for (int nt = 0; nt < 4; ++nt) {
                    bf16x8 b = *(const bf16x8*)
                        &sB[(nt * 32 + c32) * LDBW + ks * 16 + hi * 8];
                    acc[nt] = __builtin_amdgcn_mfma_f32_32x32x16_bf16(
                        a[j], b, acc[nt], 0, 0, 0);
                }
            }
        }

        float p[16];
        #pragma unroll
        for (int r = 0; r < 16; ++r) {
            float s = 0.f;
            #pragma unroll
            for (int nt = 0; nt < 4; ++nt)
                s += fmaxf(acc[nt][r] + b1v[nt], 0.f) * w2v[nt];
            p[r] = s;
        }
        #pragma unroll
        for (int off = 1; off < 32; off <<= 1)
            #pragma unroll
            for (int r = 0; r < 16; ++r)
                p[r] += __shfl_xor(p[r], off, 64);
        if (c32 == 0) {
            #pragma unroll
            for (int r = 0; r < 16; ++r)
                sLog[w][(r & 3) + 8 * (r >> 2) + 4 * hi] = p[r];
        }
        float x  = sLog[w][c32] + b2v;
        float sg = 1.f / (1.f + __expf(-x));
        if (hi == 0 && e < E) out[e] = sg;
    }
}

extern "C" void kernel_launch(void* const* d_in, const int* in_sizes, int n_in,
                              void* d_out, int out_size, void* d_ws, size_t ws_size,
                              hipStream_t stream) {
    const float* pat  = (const float*)d_in[0];
    const float* cond = (const float*)d_in[1];
    const int*   eidx = (const int*)d_in[2];     // int64 in reference -> int32 on device
    const float* W1   = (const float*)d_in[3];
    const float* b1   = (const float*)d_in[4];
    const float* W2   = (const float*)d_in[5];
    const float* b2   = (const float*)d_in[6];
    float*       out  = (float*)d_out;

    const int E       = in_sizes[2] / 2;
    const int n_nodes = in_sizes[0] / IN_DIM;
    const int ntiles  = (E + TILE_E - 1) / TILE_E;

    // ws layout: [0,64K) W1T bf16 | pat_bf | cond_bf
    unsigned short* W1T = (unsigned short*)d_ws;
    const size_t tbl_bytes = (size_t)n_nodes * IN_DIM * 2;
    unsigned short* pat_bf  = (unsigned short*)((char*)d_ws + 65536);
    unsigned short* cond_bf = (unsigned short*)((char*)d_ws + 65536 + tbl_bytes);
    const bool use_tbl = ws_size >= 65536 + 2 * tbl_bytes;

    const int n_vec = n_nodes * IN_DIM / 8;
    prep_kernel<<<2048, 256, 0, stream>>>(pat, cond, W1, pat_bf, cond_bf, W1T,
                                          n_vec, use_tbl ? 1 : 0);

    const int nblocks = 256;   // 1 block/CU (8 waves, 2/EU): deliberate ILP regime
    if (use_tbl) {
        link_mlp_kernel<<<nblocks, NTHREADS, 0, stream>>>(
            pat_bf, cond_bf, eidx, W1T, b1, W2, b2, out, E, n_nodes, ntiles);
    } else {
        link_mlp_f32_kernel<<<nblocks, NTHREADS, 0, stream>>>(
            pat, cond, eidx, W1T, b1, W2, b2, out, E, n_nodes, ntiles);
    }
}